// Round 7
// baseline (143.376 us; speedup 1.0000x reference)
//
#include <hip/hip_runtime.h>
#include <math.h>

#define HH 1024
#define WW 1024
#define OUTW 58            // output columns per wave (64 lanes - 6 halo)
#define RPB 4              // output rows per WAVE (vertical slide length)
#define WPB 4              // waves per block (independent y-strips, no barrier)
#define OFF(i) ((i)*8 - (i)*((i)-1)/2)   // packed upper-tri row offset

// Round-4 lesson: forcing a VGPR cap below the ~128-reg working set via
// launch_bounds -> 1.2 GB scratch spill, 3x regression. (WPB*64, 2) gives the
// allocator a 256-VGPR ceiling: no spill, natural allocation.

// DPP move, bound_ctrl=1 (invalid lanes read 0)
template<int CTRL>
__device__ __forceinline__ float dpp0(float x) {
    return __int_as_float(
        __builtin_amdgcn_update_dpp(0, __float_as_int(x), CTRL, 0xf, 0xf, true));
}
// whole-wave shift right by 1 lane (crosses 16-lane row boundaries)
__device__ __forceinline__ float wshr1(float x) { return dpp0<0x138>(x); }

// fp32 reciprocal: v_rcp_f32 + 1 Newton step (~1ulp); no sqrt anywhere in the
// LDL^T path -> much shorter serial chain than Cholesky's 8 rsqrt chains
__device__ __forceinline__ float frcp_fast(float s) {
    float r = __builtin_amdgcn_rcpf(s);
    return r * fmaf(-s, r, 2.0f);
}

__global__ __launch_bounds__(WPB * 64, 2) void ls_sep_kernel(
    const float* __restrict__ inp,    // [3,H,W]
    const float* __restrict__ dep,    // [1,H,W]
    const float* __restrict__ alb,    // [3,H,W]
    const float* __restrict__ nrm,    // [3,H,W]
    float* __restrict__ out)          // [3,H,W]
{
    const int L  = threadIdx.x & 63;          // lane 0..63
    const int wv = threadIdx.x >> 6;          // wave 0..3 (independent y-strip)
    const int HW = HH * WW;
    // lane L sums column x; its horizontal window (x-6..x) is centered at x-3
    const int x  = OUTW * blockIdx.x - 3 + L;
    const int y0 = (RPB * WPB) * blockIdx.y + RPB * wv;
    const int px = x - 3;                     // output pixel column for this lane

    const int xc    = min(max(x, 0), WW - 1);
    const float xok = (x >= 0 && x < WW) ? 1.f : 0.f;

    float C[60];                              // running column sums (7 rows in y)
    #pragma unroll
    for (int k = 0; k < 60; k++) C[k] = 0.f;

    // load one image row's 10 values for this lane's column (clamped addr)
    auto load_row = [&](int yy, float fv[7], float yv[3]) -> float {
        const int yc = min(max(yy, 0), HH - 1);
        const float ok = (yy >= 0 && yy < HH) ? xok : 0.f;
        const int p = yc * WW + xc;
        fv[0] = dep[p];
        fv[1] = alb[p]; fv[2] = alb[p + HW]; fv[3] = alb[p + 2 * HW];
        fv[4] = nrm[p]; fv[5] = nrm[p + HW]; fv[6] = nrm[p + 2 * HW];
        yv[0] = inp[p]; yv[1] = inp[p + HW]; yv[2] = inp[p + 2 * HW];
        return ok;
    };
    // accumulate a loaded row into the column sums with signed validity s
    auto acc_regs = [&](const float fv[7], const float yv[3], float s) {
        float f8[8];
        f8[0] = 1.f;
        #pragma unroll
        for (int i = 0; i < 7; i++) f8[i + 1] = fv[i];
        float fs[8];
        #pragma unroll
        for (int i = 0; i < 8; i++) fs[i] = f8[i] * s;
        int k = 0;
        #pragma unroll
        for (int i = 0; i < 8; i++)
            #pragma unroll
            for (int j = i; j < 8; j++) { C[k] = fmaf(fs[i], f8[j], C[k]); k++; }
        #pragma unroll
        for (int i = 0; i < 8; i++)
            #pragma unroll
            for (int c = 0; c < 3; c++)
                C[36 + i * 3 + c] = fmaf(fs[i], yv[c], C[36 + i * 3 + c]);
    };

    // preload full window of first output row: rows y0-3 .. y0+3
    #pragma unroll 1
    for (int yy = y0 - 3; yy <= y0 + 3; yy++) {
        float fv[7], yv[3];
        const float ok = load_row(yy, fv, yv);
        acc_regs(fv, yv, ok);
    }

    const int idxm4 = ((L - 4) & 63) << 2;    // bpermute byte index for lane L-4
    const int pxc = min(max(px, 0), WW - 1);
    const bool do_store = (L >= 6) && (px < WW);

    #pragma unroll 1
    for (int y = y0; y < y0 + RPB; y++) {
        // ---- exact horizontal 7-tap: S(L) = sum of C over lanes L-6..L ----
        float S[60];
        #pragma unroll
        for (int k = 0; k < 60; k++) {
            const float xv = C[k];
            const float w1 = wshr1(xv);       // C(L-1)
            const float t1 = xv + w1;         // L-1..L
            const float w2 = wshr1(w1);       // C(L-2)
            const float t3 = t1 + w2;         // L-2..L
            const float w3 = wshr1(w2);       // C(L-3)
            const float t2 = t3 + w3;         // L-3..L
            const float pm = __int_as_float(
                __builtin_amdgcn_ds_bpermute(idxm4, __float_as_int(t3))); // L-6..L-4
            S[k] = t2 + pm;
        }

        // ---- prefetch next enter/leave rows NOW; consumed after the solve,
        //      so the ~1.5k-cycle solve hides their latency ----
        float fE[7], yE[3], fL[7], yL[3];
        const float okE = load_row(y + 4, fE, yE);
        const float okL = load_row(y - 3, fL, yL);

        // center-pixel features (row y was fetched 3 iters ago -> L2-warm)
        const int pc = y * WW + pxc;
        float cf[8];
        cf[0] = 1.f;
        cf[1] = dep[pc];
        cf[2] = alb[pc]; cf[3] = alb[pc + HW]; cf[4] = alb[pc + 2 * HW];
        cf[5] = nrm[pc]; cf[6] = nrm[pc + HW]; cf[7] = nrm[pc + 2 * HW];

        // ---- fp32 LDL^T of AtA (+eps I), packed upper-tri, sqrt-free ----
        // W row i stores R_ij = d_i * U_ij (unscaled); d_i = R_ii
        float W[36];
        #pragma unroll
        for (int k = 0; k < 36; k++) W[k] = S[k];
        #pragma unroll
        for (int i = 0; i < 8; i++) W[OFF(i)] += 1.0e-4f;

        float idv[8];
        #pragma unroll
        for (int i = 0; i < 8; i++) {
            #pragma unroll
            for (int k = 0; k < i; k++) {
                const float c = W[OFF(k) + i - k] * idv[k];   // U_ki
                #pragma unroll
                for (int j = i; j < 8; j++)
                    W[OFF(i) + j - i] = fmaf(-c, W[OFF(k) + j - k], W[OFF(i) + j - i]);
            }
            idv[i] = frcp_fast(W[OFF(i)]);    // 1/d_i
        }

        // forward: vt_i = idv_i * (cf_i - sum_{k<i} R_ki * vt_k)
        float vt[8];
        #pragma unroll
        for (int i = 0; i < 8; i++) {
            float s = cf[i];
            #pragma unroll
            for (int k = 0; k < i; k++)
                s = fmaf(-W[OFF(k) + i - k], vt[k], s);
            vt[i] = s * idv[i];
        }
        // back: w_i = vt_i - idv_i * sum_{j>i} R_ij * w_j
        float w[8];
        #pragma unroll
        for (int i = 7; i >= 0; i--) {
            float t = 0.f;
            #pragma unroll
            for (int j = i + 1; j < 8; j++)
                t = fmaf(W[OFF(i) + j - i], w[j], t);
            w[i] = fmaf(-idv[i], t, vt[i]);
        }

        if (do_store) {
            const int p = y * WW + px;
            #pragma unroll
            for (int c = 0; c < 3; c++) {
                float r = 0.f;
                #pragma unroll
                for (int i = 0; i < 8; i++)
                    r = fmaf(w[i], S[36 + i * 3 + c], r);
                out[c * HW + p] = r;
            }
        }

        // ---- slide window: add entering row y+4, drop leaving row y-3 ----
        // (unconditional: last iteration's update is wasted but keeps the
        //  prefetch loads unconditional so the scheduler can't sink them)
        acc_regs(fE, yE, okE);
        acc_regs(fL, yL, -okL);
    }
}

extern "C" void kernel_launch(void* const* d_in, const int* in_sizes, int n_in,
                              void* d_out, int out_size, void* d_ws, size_t ws_size,
                              hipStream_t stream) {
    const float* inp = (const float*)d_in[0];
    const float* dep = (const float*)d_in[1];
    const float* alb = (const float*)d_in[2];
    const float* nrm = (const float*)d_in[3];
    float* out = (float*)d_out;
    dim3 grid((WW + OUTW - 1) / OUTW, HH / (RPB * WPB));   // 18 x 64, 256-thr blocks
    ls_sep_kernel<<<grid, dim3(WPB * 64), 0, stream>>>(inp, dep, alb, nrm, out);
}

// Round 9
// 127.622 us; speedup vs baseline: 1.1234x; 1.1234x over previous
//
#include <hip/hip_runtime.h>
#include <math.h>

#define HH 1024
#define WW 1024
#define OUTW 58            // output columns per wave (64 lanes - 6 halo)
#define RPB 4              // output rows per WAVE (vertical slide length)
#define WPB 4              // waves per block (independent y-strips, no barrier)
#define OFF(i) ((i)*8 - (i)*((i)-1)/2)   // packed upper-tri row offset

// Round-4 lesson: forcing a VGPR cap below the working set -> 1.2 GB spill.
// Round-7 lesson: peak live floats must stay <= ~120 or the allocator spills
// at VGPR=128 even when 256 is permitted (40 MB scratch, 1.5x regression).
// Round-8 lesson: cross-lane ops (DPP/bpermute) must NEVER sit inside
// lane-divergent control flow — EXEC-masked neighbors read as 0/undefined.

// DPP move, bound_ctrl=1 (invalid lanes read 0)
template<int CTRL>
__device__ __forceinline__ float dpp0(float x) {
    return __int_as_float(
        __builtin_amdgcn_update_dpp(0, __float_as_int(x), CTRL, 0xf, 0xf, true));
}
// whole-wave shift right by 1 lane (crosses 16-lane row boundaries)
__device__ __forceinline__ float wshr1(float x) { return dpp0<0x138>(x); }

// fp32 reciprocal: v_rcp_f32 + 1 Newton step (~1ulp); LDL^T is sqrt-free
__device__ __forceinline__ float frcp_fast(float s) {
    float r = __builtin_amdgcn_rcpf(s);
    return r * fmaf(-s, r, 2.0f);
}

__global__ __launch_bounds__(WPB * 64, 2) void ls_sep_kernel(
    const float* __restrict__ inp,    // [3,H,W]
    const float* __restrict__ dep,    // [1,H,W]
    const float* __restrict__ alb,    // [3,H,W]
    const float* __restrict__ nrm,    // [3,H,W]
    float* __restrict__ out)          // [3,H,W]
{
    const int L  = threadIdx.x & 63;          // lane 0..63
    const int wv = threadIdx.x >> 6;          // wave 0..3 (independent y-strip)
    const int HW = HH * WW;
    // lane L sums column x; its horizontal window (x-6..x) is centered at x-3
    const int x  = OUTW * blockIdx.x - 3 + L;
    const int y0 = (RPB * WPB) * blockIdx.y + RPB * wv;
    const int px = x - 3;                     // output pixel column for this lane

    const int xc    = min(max(x, 0), WW - 1);
    const float xok = (x >= 0 && x < WW) ? 1.f : 0.f;

    float C[60];                              // running column sums (7 rows in y)
    #pragma unroll
    for (int k = 0; k < 60; k++) C[k] = 0.f;

    auto acc_row = [&](int yy, float sgn) {
        const int yc = min(max(yy, 0), HH - 1);
        const float ok = (yy >= 0 && yy < HH) ? xok : 0.f;
        const int p = yc * WW + xc;
        float fv[8], yv[3];
        fv[0] = 1.f;
        fv[1] = dep[p];
        fv[2] = alb[p];
        fv[3] = alb[p + HW];
        fv[4] = alb[p + 2 * HW];
        fv[5] = nrm[p];
        fv[6] = nrm[p + HW];
        fv[7] = nrm[p + 2 * HW];
        yv[0] = inp[p];
        yv[1] = inp[p + HW];
        yv[2] = inp[p + 2 * HW];
        const float s = sgn * ok;
        float fs[8];
        #pragma unroll
        for (int i = 0; i < 8; i++) fs[i] = fv[i] * s;
        int k = 0;
        #pragma unroll
        for (int i = 0; i < 8; i++)
            #pragma unroll
            for (int j = i; j < 8; j++) { C[k] = fmaf(fs[i], fv[j], C[k]); k++; }
        #pragma unroll
        for (int i = 0; i < 8; i++)
            #pragma unroll
            for (int c = 0; c < 3; c++)
                C[36 + i * 3 + c] = fmaf(fs[i], yv[c], C[36 + i * 3 + c]);
    };

    // preload rows y0-4 .. y0+2 (loop body does add(y+3), sub(y-4))
    #pragma unroll 1
    for (int yy = y0 - 4; yy < y0 + 3; yy++) acc_row(yy, 1.f);

    const int idxm4 = ((L - 4) & 63) << 2;    // bpermute byte index for lane L-4
    const int pxc = min(max(px, 0), WW - 1);
    const bool do_store = (L >= 6) && (px < WW);

    // horizontal 7-tap over lanes L-6..L of a column-sum value.
    // MUST be called by all 64 lanes (cross-lane DPP + bpermute inside).
    auto htap = [&](float xv) -> float {
        const float w1 = wshr1(xv);           // C(L-1)
        const float t1 = xv + w1;             // L-1..L
        const float w2 = wshr1(w1);           // C(L-2)
        const float t3 = t1 + w2;             // L-2..L
        const float w3 = wshr1(w2);           // C(L-3)
        const float t2 = t3 + w3;             // L-3..L
        const float pm = __int_as_float(
            __builtin_amdgcn_ds_bpermute(idxm4, __float_as_int(t3))); // L-6..L-4
        return t2 + pm;
    };

    #pragma unroll 1
    for (int y = y0; y < y0 + RPB; y++) {
        acc_row(y + 3, 1.f);
        acc_row(y - 4, -1.f);

        // ---- horizontal taps for AtA only (AtY deferred past the solve to
        //      keep peak live registers < ~120: round-7 spill lesson) ----
        float W[36];
        #pragma unroll
        for (int k = 0; k < 36; k++) W[k] = htap(C[k]);
        #pragma unroll
        for (int i = 0; i < 8; i++) W[OFF(i)] += 1.0e-4f;

        // center-pixel features (column px, row y)
        const int pc = y * WW + pxc;
        float cf[8];
        cf[0] = 1.f;
        cf[1] = dep[pc];
        cf[2] = alb[pc]; cf[3] = alb[pc + HW]; cf[4] = alb[pc + 2 * HW];
        cf[5] = nrm[pc]; cf[6] = nrm[pc + HW]; cf[7] = nrm[pc + 2 * HW];

        // ---- fp32 LDL^T (sqrt-free). W row i keeps R_ij = d_i*U_ij ----
        float idv[8];
        #pragma unroll
        for (int i = 0; i < 8; i++) {
            #pragma unroll
            for (int k = 0; k < i; k++) {
                const float c = W[OFF(k) + i - k] * idv[k];   // U_ki
                #pragma unroll
                for (int j = i; j < 8; j++)
                    W[OFF(i) + j - i] = fmaf(-c, W[OFF(k) + j - k], W[OFF(i) + j - i]);
            }
            idv[i] = frcp_fast(W[OFF(i)]);    // 1/d_i
        }

        // forward: vt_i = idv_i * (cf_i - sum_{k<i} R_ki * vt_k)
        float vt[8];
        #pragma unroll
        for (int i = 0; i < 8; i++) {
            float s = cf[i];
            #pragma unroll
            for (int k = 0; k < i; k++)
                s = fmaf(-W[OFF(k) + i - k], vt[k], s);
            vt[i] = s * idv[i];
        }
        // back: w_i = vt_i - idv_i * sum_{j>i} R_ij * w_j
        float w[8];
        #pragma unroll
        for (int i = 7; i >= 0; i--) {
            float t = 0.f;
            #pragma unroll
            for (int j = i + 1; j < 8; j++)
                t = fmaf(W[OFF(i) + j - i], w[j], t);
            w[i] = fmaf(-idv[i], t, vt[i]);
        }

        // ---- deferred AtY taps + output dot products: ALL lanes execute
        //      (htap is cross-lane); only the store is predicated ----
        float r[3];
        #pragma unroll
        for (int c = 0; c < 3; c++) {
            float acc = 0.f;
            #pragma unroll
            for (int i = 0; i < 8; i++)
                acc = fmaf(w[i], htap(C[36 + i * 3 + c]), acc);
            r[c] = acc;
        }

        if (do_store) {
            const int p = y * WW + px;
            #pragma unroll
            for (int c = 0; c < 3; c++)
                out[c * HW + p] = r[c];
        }
    }
}

extern "C" void kernel_launch(void* const* d_in, const int* in_sizes, int n_in,
                              void* d_out, int out_size, void* d_ws, size_t ws_size,
                              hipStream_t stream) {
    const float* inp = (const float*)d_in[0];
    const float* dep = (const float*)d_in[1];
    const float* alb = (const float*)d_in[2];
    const float* nrm = (const float*)d_in[3];
    float* out = (float*)d_out;
    dim3 grid((WW + OUTW - 1) / OUTW, HH / (RPB * WPB));   // 18 x 64, 256-thr blocks
    ls_sep_kernel<<<grid, dim3(WPB * 64), 0, stream>>>(inp, dep, alb, nrm, out);
}